// Round 9
// baseline (379.103 us; speedup 1.0000x reference)
//
#include <hip/hip_runtime.h>

#define BATCH 8192
#define V 512
#define N1 513
#define KCH 16
#define NCHUNKS 32
#define RB 32            // rows per block -> grid 256, 1 block/CU
#define NT 1024          // 16 waves; wave w: chain rows 2w,2w+1, j-tiles 2w,2w+1
#define PKS 520          // Phi row stride (bf16 elems)
#define SJP 772          // padded S row stride (dwords): col j at 12*(j>>3)+(j&7)

typedef __bf16 bf16_t;
typedef bf16_t bf16x8 __attribute__((ext_vector_type(8)));
typedef float f32x4 __attribute__((ext_vector_type(4)));
typedef float f32x2 __attribute__((ext_vector_type(2)));

// workspace: Mhi (fragment-linear triangular pack, mat=1 tiles PRE-NEGATED),
// Dv (fp32, pre-scaled by mat sign), Bv (fp32, pre-negated mat=1).
#define EPP 4194304ull
#define DV_OFF (EPP * 2ull)
#define BV_OFF (DV_OFF + 1048576ull)

__device__ __forceinline__ f32x4 mfma16(bf16x8 a, bf16x8 b, f32x4 c) {
    return __builtin_amdgcn_mfma_f32_16x16x32_bf16(a, b, c, 0, 0, 0);
}

__device__ __forceinline__ float bcast_lane(float x, int l) {
    return __int_as_float(__builtin_amdgcn_readlane(__float_as_int(x), l));
}

__device__ __forceinline__ float dpp_xor1_max(float x) {
    const int xi = __float_as_int(x);
    const float o = __int_as_float(
        __builtin_amdgcn_update_dpp(xi, xi, 0xB1, 0xF, 0xF, false));
    return fmaxf(x, o);
}

// ---- unified repack (unchanged from R5) -----------------------------------
__global__ __launch_bounds__(1024)
void repack_all(const float* __restrict__ pos, const float* __restrict__ neg,
                bf16_t* __restrict__ Mhi, float* __restrict__ Dv,
                float* __restrict__ Bv)
{
    __shared__ float sb[2 * 256 * 36];   // 73,728 B
    const int bx  = blockIdx.x;
    const int tid = threadIdx.x;
    if (bx < 496) {
        const int cc  = (bx >> 4) + 1;       // 1..31
        const int kb  = bx & 15;
        const int nkb = (cc + 1) >> 1;
        if (kb >= nkb) return;
        const int klen = 16 * cc;
        for (int idx = tid; idx < 8192; idx += 1024) {
            const int r = idx >> 5, k32 = idx & 31;
            const int k = kb * 32 + k32;
            const size_t row = (size_t)cc * 256 + r;
            float xp = 0.0f, xn = 0.0f;
            if (k < klen) {
                xp = pos[row * N1 + k];
                xn = -neg[row * N1 + k];     // pre-negate mat=1
            }
            sb[r * 36 + k32]            = xp;
            sb[256 * 36 + r * 36 + k32] = xn;
        }
        __syncthreads();
        const size_t base = 16384ull * (size_t)((cc * cc) / 4) + (size_t)kb * 16384ull;
        for (int e8 = tid; e8 < 2048; e8 += 1024) {
            const int t = e8 >> 6, s = e8 & 63;
            const int c = s & 15, q = s >> 4;
            const int vloc = t >> 1, m = t & 1;
            const float* sp = &sb[m * 256 * 36 + (vloc * 16 + c) * 36 + 8 * q];
            bf16x8 o;
            #pragma unroll
            for (int jj = 0; jj < 8; ++jj) o[jj] = (bf16_t)sp[jj];
            *(bf16x8*)(Mhi + base + (size_t)e8 * 8) = o;
        }
    } else {
        const int cc = bx - 496;             // 0..31, one block per chunk
        float* bufP = sb;                    // stride-17 views
        float* bufN = sb + 256 * 17;
        for (int idx = tid; idx < 4096; idx += 1024) {
            const int r = idx >> 4, kk = idx & 15;
            const size_t row = (size_t)(cc * 256 + r);
            bufP[r * 17 + kk] = pos[row * N1 + cc * 16 + kk];
            bufN[r * 17 + kk] = neg[row * N1 + cc * 16 + kk];
        }
        __syncthreads();
        for (int idx = tid; idx < 8192; idx += 1024) {
            const int vl = idx >> 9, j = idx & 511;
            const int vlo = j >> 5, c = j & 15;
            const int m = (j >> 4) & 1;
            const float x = (m ? bufN : bufP)[(vlo * 16 + c) * 17 + vl];
            Dv[(size_t)cc * 8192 + idx] = m ? -x : x;
        }
        for (int j = tid; j < 512; j += 1024) {
            const int vlo = j >> 5, c = j & 15;
            const int m = (j >> 4) & 1;
            const float* src = m ? neg : pos;
            const float x = src[(size_t)(cc * 256 + vlo * 16 + c) * N1 + V];
            Bv[(size_t)cc * 512 + j] = m ? -x : x;
        }
    }
}

// ---- fused main kernel R9: R1 geometry + R7's Dv-LDS dedup --------------------
// R1 (32 rows/block, 2 rows/wave, acc[2][2]) is the fb-efficient geometry:
// each wave's 2KB fb per k-block serves 32 output rows (16-row blocks pay 2x).
// R7 proved deduping Dv through LDS is worth ~100us in the 16-row shape; here
// it removes R1's 16x2KB/step redundant global Dv stream. Stage is IN-PLACE
// between barriers B and C (~400cy x 32 chunks ~ 2% -- the split-issue variant
// spilled in R8; do not hold staged regs across the dump). dv LDS read plain
// stride-8 (R8 proved the XOR swizzle is a null). Registers: identical live
// set to R1 (64 arch, no spill) minus per-step global addressing.
// Numerics bit-identical to R1 -> absmax 8.0. Spill tell: WRITE_SIZE >> 17MB.
__global__ __launch_bounds__(NT, 4)
void shield_fused(const float* __restrict__ preds,
                  const bf16_t* __restrict__ Mhi,
                  const float* __restrict__ Dv, const float* __restrict__ Bv,
                  float* __restrict__ out)
{
    __shared__ bf16_t Phi[RB * PKS];   // 33,280 B
    __shared__ float  S[RB * SJP];     // 98,816 B (total 132,096 -> 1 block/CU)
                                       // first 8192 dwords double as Dv_lds[16][512]

    const int tid  = threadIdx.x;
    const int b0   = blockIdx.x * RB;
    const int lane = tid & 63;
    const int w    = tid >> 6;          // 0..15
    const int cq   = lane & 15;
    const int q    = lane >> 4;
    const int rp0  = w * 2;             // chain rows 2w, 2w+1

    // ---- load preds -> Phi ----
    {
        const int r = tid >> 5, seg = tid & 31;
        const float* prow = preds + (size_t)(b0 + r) * V + seg * 16;
        #pragma unroll
        for (int k = 0; k < 16; k += 4) {
            const float4 p4 = *(const float4*)(prow + k);
            const int n = seg * 16 + k;
            Phi[r * PKS + n + 0] = (bf16_t)p4.x;
            Phi[r * PKS + n + 1] = (bf16_t)p4.y;
            Phi[r * PKS + n + 2] = (bf16_t)p4.z;
            Phi[r * PKS + n + 3] = (bf16_t)p4.w;
        }
    }

    int tJ[2], sct[2];
    #pragma unroll
    for (int tt = 0; tt < 2; ++tt) {
        tJ[tt]  = ((2 * w + tt) << 4) + cq;
        sct[tt] = 12 * (tJ[tt] >> 3) + (tJ[tt] & 7);   // padded S column
    }
    const int aoff0 = cq * PKS + 8 * q;
    const int aoff1 = (16 + cq) * PKS + 8 * q;

    // acc(0) = bias(0)
    f32x4 acc[2][2];
    #pragma unroll
    for (int tt = 0; tt < 2; ++tt) {
        const float b = Bv[tJ[tt]];
        acc[0][tt] = f32x4{b, b, b, b};
        acc[1][tt] = f32x4{b, b, b, b};
    }

    #pragma unroll 1
    for (int cc = 0; cc < NCHUNKS; ++cc) {
        const int v0 = cc * 16;
        const int  ccn  = cc + 1;
        const bool hasN = ccn < NCHUNKS;
        const int  nkbN = hasN ? ((ccn + 1) >> 1) : 0;
        const bf16_t* phN = Mhi + 16384ull * (size_t)((ccn * ccn) / 4)
                          + (size_t)lane * 8 + (size_t)(2 * w) * 512;

        // ---- dump acc(cc) -> S (padded columns) ----
        #pragma unroll
        for (int tt = 0; tt < 2; ++tt)
            #pragma unroll
            for (int reg = 0; reg < 4; ++reg) {
                S[(4 * q + reg) * SJP + sct[tt]]      = acc[0][tt][reg];
                S[(16 + 4 * q + reg) * SJP + sct[tt]] = acc[1][tt][reg];
            }
        __syncthreads();   // (A) S ready; prior Phi writes visible

        // ---- load s2: lane owns j = 8*lane..8*lane+7, rows 2w / 2w+1 ----
        f32x2 s2[8];
        {
            const float* sp = &S[rp0 * SJP + 12 * lane];
            const float4 a0 = *(const float4*)(sp);
            const float4 a1 = *(const float4*)(sp + 4);
            const float4 c0 = *(const float4*)(sp + SJP);
            const float4 c1 = *(const float4*)(sp + SJP + 4);
            s2[0] = f32x2{a0.x, c0.x}; s2[1] = f32x2{a0.y, c0.y};
            s2[2] = f32x2{a0.z, c0.z}; s2[3] = f32x2{a0.w, c0.w};
            s2[4] = f32x2{a1.x, c1.x}; s2[5] = f32x2{a1.y, c1.y};
            s2[6] = f32x2{a1.z, c1.z}; s2[7] = f32x2{a1.w, c1.w};
        }

        // ---- prefetch this chunk's po values (cols v0..v0+15, both rows) ----
        const bf16x8 poA0 = *(const bf16x8*)(Phi + rp0 * PKS + v0);
        const bf16x8 poA1 = *(const bf16x8*)(Phi + rp0 * PKS + v0 + 8);
        const bf16x8 poB0 = *(const bf16x8*)(Phi + (rp0 + 1) * PKS + v0);
        const bf16x8 poB1 = *(const bf16x8*)(Phi + (rp0 + 1) * PKS + v0 + 8);

        // ---- init acc(ccn) with bias ----
        if (hasN) {
            #pragma unroll
            for (int tt = 0; tt < 2; ++tt) {
                const float b = Bv[(ccn << 9) + tJ[tt]];
                acc[0][tt] = f32x4{b, b, b, b};
                acc[1][tt] = f32x4{b, b, b, b};
            }
        }

        __syncthreads();   // (B) all s2 reads done; S region reusable

        // ---- stage Dv(cc) into the dead S region: wave w stages v-row w ----
        // (in-place: load + write adjacent; transient regs only)
        {
            const float* src = Dv + (((size_t)cc * 16 + w) << 9) + 8 * lane;
            const float4 a = *(const float4*)(src);
            const float4 b = *(const float4*)(src + 4);
            float* dst = S + w * 512 + 8 * lane;
            *(float4*)(dst)     = a;
            *(float4*)(dst + 4) = b;
        }
        __syncthreads();   // (C) Dv_lds ready

        // ---- 16-step serial chain + interleaved bulk GEMM of chunk ccn ----
        #pragma unroll
        for (int vl = 0; vl < KCH; ++vl) {
            const int vcur = v0 + vl;
            const bool doKb = hasN && (vl < nkbN - 1);

            bf16x8 fa0, fa1, fb0, fb1;
            if (doKb) {
                const int k0 = vl * 32;
                fa0 = *(const bf16x8*)(Phi + aoff0 + k0);
                fa1 = *(const bf16x8*)(Phi + aoff1 + k0);
                const bf16_t* pb = phN + (size_t)k0 * 512;
                fb0 = *(const bf16x8*)(pb);
                fb1 = *(const bf16x8*)(pb + 512);
            }

            // this step's dv from LDS (shared across all 16 waves)
            float dv[8];
            {
                const float* dls = S + vl * 512 + 8 * lane;
                const float4 d0 = *(const float4*)(dls);
                const float4 d1 = *(const float4*)(dls + 4);
                dv[0]=d0.x; dv[1]=d0.y; dv[2]=d0.z; dv[3]=d0.w;
                dv[4]=d1.x; dv[5]=d1.y; dv[6]=d1.z; dv[7]=d1.w;
            }
            const float po_[2] = {
                (float)(vl < 8 ? poA0[vl & 7] : poA1[vl & 7]),
                (float)(vl < 8 ? poB0[vl & 7] : poB1[vl & 7])
            };

            // in-lane reduce 8 -> 1 per row (max3-fusable), xor-1 merge via DPP
            float red[2];
            #pragma unroll
            for (int r = 0; r < 2; ++r) {
                const float m0 = fmaxf(fmaxf(s2[0][r], s2[1][r]), s2[2][r]);
                const float m1 = fmaxf(fmaxf(s2[3][r], s2[4][r]), s2[5][r]);
                const float m2 = fmaxf(s2[6][r], s2[7][r]);
                const float mxr = fmaxf(fmaxf(m0, m1), m2);
                red[r] = dpp_xor1_max(mxr);
            }
            // broadcast from compile-time lanes via v_readlane (no DS op)
            float pc[2];
            #pragma unroll
            for (int r = 0; r < 2; ++r) {
                const float lw  = bcast_lane(red[r], 4 * vl);       // lower
                const float nup = bcast_lane(red[r], 4 * vl + 2);   // -upper
                pc[r] = fminf(fmaxf(po_[r], lw), -nup);
            }
            if (lane == 4 * vl) {
                Phi[rp0 * PKS + vcur]       = (bf16_t)pc[0];
                Phi[(rp0 + 1) * PKS + vcur] = (bf16_t)pc[1];
            }
            // rank-1 update (packed fp32 fma; Dv pre-scaled so no sign mul)
            const f32x2 pcv = {pc[0], pc[1]};
            #pragma unroll
            for (int jj = 0; jj < 8; ++jj) {
                const f32x2 dsp = {dv[jj], dv[jj]};
                s2[jj] = __builtin_elementwise_fma(dsp, pcv, s2[jj]);
            }

            if (doKb) {
                acc[0][0] = mfma16(fa0, fb0, acc[0][0]);
                acc[1][0] = mfma16(fa1, fb0, acc[1][0]);
                acc[0][1] = mfma16(fa0, fb1, acc[0][1]);
                acc[1][1] = mfma16(fa1, fb1, acc[1][1]);
            }
        }

        __syncthreads();   // (D) fresh Phi visible; S safe for next dump

        // ---- final k-block of chunk ccn (zero-padded B -> exact no-ops) ----
        if (hasN) {
            const int k0 = (nkbN - 1) * 32;
            const bf16x8 fa0 = *(const bf16x8*)(Phi + aoff0 + k0);
            const bf16x8 fa1 = *(const bf16x8*)(Phi + aoff1 + k0);
            const bf16_t* pb = phN + (size_t)k0 * 512;
            const bf16x8 fb0 = *(const bf16x8*)(pb);
            const bf16x8 fb1 = *(const bf16x8*)(pb + 512);
            acc[0][0] = mfma16(fa0, fb0, acc[0][0]);
            acc[1][0] = mfma16(fa1, fb0, acc[1][0]);
            acc[0][1] = mfma16(fa0, fb1, acc[0][1]);
            acc[1][1] = mfma16(fa1, fb1, acc[1][1]);
        }
    }

    // ---- epilogue ----
    {
        const int r = tid >> 5, seg = tid & 31;
        float* orow = out + (size_t)(b0 + r) * V + seg * 16;
        #pragma unroll
        for (int k = 0; k < 16; k += 4) {
            const int n = seg * 16 + k;
            float4 o;
            o.x = (float)Phi[r * PKS + n + 0];
            o.y = (float)Phi[r * PKS + n + 1];
            o.z = (float)Phi[r * PKS + n + 2];
            o.w = (float)Phi[r * PKS + n + 3];
            *(float4*)(orow + k) = o;
        }
    }
}

extern "C" void kernel_launch(void* const* d_in, const int* in_sizes, int n_in,
                              void* d_out, int out_size, void* d_ws, size_t ws_size,
                              hipStream_t stream) {
    const float* preds = (const float*)d_in[0];
    const float* pos   = (const float*)d_in[1];
    const float* neg   = (const float*)d_in[2];
    float* o = (float*)d_out;
    char* base = (char*)d_ws;
    bf16_t* Mhi = (bf16_t*)base;
    float*  Dv  = (float*)(base + DV_OFF);
    float*  Bv  = (float*)(base + BV_OFF);
    repack_all<<<dim3(528), 1024, 0, stream>>>(pos, neg, Mhi, Dv, Bv);
    shield_fused<<<dim3(BATCH / RB), NT, 0, stream>>>(preds, Mhi, Dv, Bv, o);
}